// Round 13
// baseline (17220.810 us; speedup 1.0000x reference)
//
#include <hip/hip_runtime.h>
#include <hip/hip_fp16.h>
#include <math.h>

#define B_   32
#define T_   400
#define BT_  12800
#define U_   1024
#define G4_  4096
#define TCH  100            // time-chunk length
#define NCH  4              // chunks per layer

typedef _Float16 f16x8 __attribute__((ext_vector_type(8)));
typedef float    f32x4 __attribute__((ext_vector_type(4)));

__device__ __forceinline__ float sigf(float x){ return 1.0f/(1.0f+expf(-x)); }
__device__ __forceinline__ int f2h2(float a, float b){
    __half2 h = __floats2half2_rn(a, b);
    return __builtin_bit_cast(int, h);
}
__device__ __forceinline__ f16x8 ldg8(const __half* p){
    return *reinterpret_cast<const f16x8*>(p);   // 16B aligned by construction
}

// Diagnostic: ws too small -> absmax ~1000 (distinct from silent-launch-fail 0.5)
__global__ __launch_bounds__(256) void ws_sentinel_kernel(float* __restrict__ out, int n)
{
    const int i = blockIdx.x * 256 + threadIdx.x;
    if (i < n) out[i] = 1000.0f;
}

// ---------------- one-time: WT[c][k] = (fp16) W[k][c], W is [rows][4096] ------
__global__ __launch_bounds__(256) void transpose_fp16_kernel(
    const float* __restrict__ W, __half* __restrict__ WT, int rowsTotal)
{
    __shared__ float tile[64][65];
    const int bx = blockIdx.x;
    const int by = blockIdx.y;
    const int tid = threadIdx.x;
    for (int i = tid; i < 1024; i += 256) {
        const int r  = i >> 4;
        const int c4 = (i & 15) * 4;
        float4 v = *(const float4*)&W[(by*64 + r)*G4_ + bx*64 + c4];
        tile[c4+0][r] = v.x; tile[c4+1][r] = v.y;
        tile[c4+2][r] = v.z; tile[c4+3][r] = v.w;
    }
    __syncthreads();
    for (int i = tid; i < 512; i += 256) {
        const int c  = i >> 3;
        const int r8 = (i & 7) * 8;
        int4 pk;
        pk.x = f2h2(tile[c][r8+0], tile[c][r8+1]);
        pk.y = f2h2(tile[c][r8+2], tile[c][r8+3]);
        pk.z = f2h2(tile[c][r8+4], tile[c][r8+5]);
        pk.w = f2h2(tile[c][r8+6], tile[c][r8+7]);
        *(int4*)&WT[(size_t)(bx*64 + c)*rowsTotal + by*64 + r8] = pk;
    }
}

// ---------------- prenet ----------------
__global__ __launch_bounds__(256) void prenet_kernel(
    const float* __restrict__ x, const float* __restrict__ pw1, const float* __restrict__ pb1,
    const float* __restrict__ pw2, const float* __restrict__ pb2, __half* __restrict__ p)
{
    __shared__ float xs[32*80];
    __shared__ float ys[32*256];
    const int r0 = blockIdx.x * 32;
    const int tid = threadIdx.x;
    for (int i = tid; i < 32*80; i += 256) xs[i] = x[r0*80 + i];
    __syncthreads();
    const int j = tid;
    float acc[32];
    #pragma unroll
    for (int r=0;r<32;r++) acc[r] = pb1[j];
    for (int k=0;k<80;k++){
        float w = pw1[k*256 + j];
        #pragma unroll
        for (int r=0;r<32;r++) acc[r] += xs[r*80+k]*w;
    }
    #pragma unroll
    for (int r=0;r<32;r++) ys[r*256+j] = fmaxf(acc[r], 0.0f);
    __syncthreads();
    #pragma unroll
    for (int r=0;r<32;r++) acc[r] = pb2[j];
    for (int k=0;k<256;k++){
        float w = pw2[k*256 + j];
        #pragma unroll
        for (int r=0;r<32;r++) acc[r] += ys[r*256+k]*w;
    }
    #pragma unroll
    for (int r=0;r<32;r++) p[(r0+r)*256 + j] = __float2half_rn(fmaxf(acc[r], 0.0f));
}

// chunk-local row (0..3199) -> global row in [12800]
__device__ __forceinline__ int groww(int l, int t0){
    const int bb = l / TCH;
    const int tt = l - bb*TCH;
    return bb*T_ + t0 + tt;
}

// ---------------- MFMA GEMM: xwc[3200,4096] = A_rows(chunk)[3200,K] @ wxT^T ---
template<int K>
__global__ __launch_bounds__(256) void gemm_mfma(
    const __half* __restrict__ A, const __half* __restrict__ BT,
    __half* __restrict__ C, int t0)
{
    const int tid  = threadIdx.x;
    const int wid  = tid >> 6;
    const int lane = tid & 63;
    const int lr   = lane & 15;
    const int kg   = lane >> 4;
    const int wrow = wid >> 1;
    const int wcol = wid & 1;
    const int row0 = blockIdx.y*64 + wrow*32;
    const int col0 = blockIdx.x*64 + wcol*32;

    const int gr0 = groww(row0 + lr,      t0);
    const int gr1 = groww(row0 + 16 + lr, t0);
    const __half* a0p = &A[(size_t)gr0*K + kg*8];
    const __half* a1p = &A[(size_t)gr1*K + kg*8];
    const __half* b0p = &BT[(size_t)(col0 + lr)*K      + kg*8];
    const __half* b1p = &BT[(size_t)(col0 + 16 + lr)*K + kg*8];

    f32x4 acc00={0,0,0,0}, acc01={0,0,0,0}, acc10={0,0,0,0}, acc11={0,0,0,0};
    for (int k0 = 0; k0 < K; k0 += 32) {
        const f16x8 a0 = ldg8(a0p + k0);
        const f16x8 a1 = ldg8(a1p + k0);
        const f16x8 b0 = ldg8(b0p + k0);
        const f16x8 b1 = ldg8(b1p + k0);
        acc00 = __builtin_amdgcn_mfma_f32_16x16x32_f16(a0, b0, acc00, 0, 0, 0);
        acc01 = __builtin_amdgcn_mfma_f32_16x16x32_f16(a0, b1, acc01, 0, 0, 0);
        acc10 = __builtin_amdgcn_mfma_f32_16x16x32_f16(a1, b0, acc10, 0, 0, 0);
        acc11 = __builtin_amdgcn_mfma_f32_16x16x32_f16(a1, b1, acc11, 0, 0, 0);
    }
    #pragma unroll
    for (int r = 0; r < 4; r++) {
        const int rA = row0 + kg*4 + r, rB = row0 + 16 + kg*4 + r;
        const int cA = col0 + lr,       cB = col0 + 16 + lr;
        C[(size_t)rA*G4_ + cA] = __float2half_rn(acc00[r]);
        C[(size_t)rA*G4_ + cB] = __float2half_rn(acc01[r]);
        C[(size_t)rB*G4_ + cA] = __float2half_rn(acc10[r]);
        C[(size_t)rB*G4_ + cB] = __float2half_rn(acc11[r]);
    }
}

// ---------------- grid barrier (generation counting, device-scope) ------------
__device__ __forceinline__ void gridbar(int* cnt, int* gen, int nblk)
{
    __syncthreads();
    if (threadIdx.x == 0) {
        __threadfence();                              // release h writes
        const int g = atomicAdd(gen, 0);
        if (atomicAdd(cnt, 1) == nblk - 1) {
            atomicExch(cnt, 0);
            __threadfence();
            atomicAdd(gen, 1);
        } else {
            while (atomicAdd(gen, 0) == g) { __builtin_amdgcn_s_sleep(8); }
        }
        __threadfence();                              // acquire
    }
    __syncthreads();
}

// ---------------- persistent MI-LSTM chunk: 100 steps, 1 launch ---------------
// 64 blocks x 256 thr (4 waves). Block owns units u0=blk*16..+15; wave = gate.
// Per step: hw = h(t-1) @ whT-cols (full K per wave, MFMA), epilogue fuses
// gates+zoneout, writes h fp16 to seq row t + fp32 carry to hb[t&1].
// One grid barrier per step (parity/aliasing proof in round-11 notes).
__global__ __launch_bounds__(256) void lstm_chunk(
    const __half* __restrict__ whT,   // [4096][1024] fp16
    const __half* __restrict__ xwc,   // [3200][4096] fp16, row = b*100 + tt
    const float* __restrict__ aP,  const float* __restrict__ b1P,
    const float* __restrict__ b2P, const float* __restrict__ biasP,
    float* __restrict__ hb0,          // fp32 carry buf (parity 0)
    float* __restrict__ hb1,          // fp32 carry buf (parity 1)
    float* __restrict__ c_st,         // [32][1024] f32, in-place
    __half* __restrict__ seq,         // [12800][1024] fp16 (recurrent h + output)
    int t0, int* bar_cnt, int* bar_gen)
{
    __shared__ float pt[4][32][17];       // [gate][batch][unit]
    __shared__ float prm[4][4][16];       // [param][gate][unit]
    const int tid  = threadIdx.x;
    const int wid  = tid >> 6;            // wave = gate
    const int lane = tid & 63;
    const int lr   = lane & 15;
    const int kg   = lane >> 4;
    const int u0   = blockIdx.x * 16;
    const int nblk = gridDim.x;

    if (tid < 64) {
        const int g = tid >> 4, j = tid & 15, col = g*U_ + u0 + j;
        prm[0][g][j] = aP[col];  prm[1][g][j] = b1P[col];
        prm[2][g][j] = b2P[col]; prm[3][g][j] = biasP[col];
    }
    __syncthreads();

    // B-frag base: wave's gate, col j=lr -> whT row wid*1024 + u0 + lr
    const __half* bp = &whT[(size_t)(wid*U_ + u0 + lr)*U_ + kg*8];

    for (int tt = 0; tt < TCH; ++tt) {
        const int t = t0 + tt;
        f32x4 acc0 = {0,0,0,0}, acc1 = {0,0,0,0};
        if (t > 0) {
            const __half* a0p = &seq[(size_t)(lr*T_      + t-1)*U_ + kg*8];
            const __half* a1p = &seq[(size_t)((lr+16)*T_ + t-1)*U_ + kg*8];
            #pragma unroll 4
            for (int ks = 0; ks < 32; ++ks) {
                const f16x8 b  = ldg8(bp  + ks*32);
                const f16x8 a0 = ldg8(a0p + ks*32);
                const f16x8 a1 = ldg8(a1p + ks*32);
                acc0 = __builtin_amdgcn_mfma_f32_16x16x32_f16(a0, b, acc0, 0, 0, 0);
                acc1 = __builtin_amdgcn_mfma_f32_16x16x32_f16(a1, b, acc1, 0, 0, 0);
            }
        }
        #pragma unroll
        for (int r = 0; r < 4; r++) {
            pt[wid][kg*4 + r][lr]      = acc0[r];
            pt[wid][16 + kg*4 + r][lr] = acc1[r];
        }
        __syncthreads();

        // epilogue: 512 outputs (32 b x 16 u), 2 per thread
        const float* hbR = (t & 1) ? hb0 : hb1;   // read hb[(t-1)&1]
        float*       hbW = (t & 1) ? hb1 : hb0;   // write hb[t&1]
        #pragma unroll
        for (int o = tid; o < 512; o += 256) {
            const int b = o >> 4, j = o & 15, u = u0 + j;
            const __half* xr = &xwc[(size_t)(b*TCH + tt)*G4_];
            float z[4];
            #pragma unroll
            for (int g = 0; g < 4; g++) {
                const float hw = pt[g][b][j];
                const float xw = __half2float(xr[g*U_ + u]);
                z[g] = prm[0][g][j]*xw*hw + prm[1][g][j]*xw + prm[2][g][j]*hw + prm[3][g][j];
            }
            const float c_old = c_st[b*U_ + u];
            const float c_new = sigf(z[1])*c_old + sigf(z[0])*tanhf(z[2]);
            const float h_new = sigf(z[3])*tanhf(c_new);
            c_st[b*U_ + u] = 0.1f*c_old + 0.9f*c_new;
            const float h_out = 0.1f*hbR[b*U_ + u] + 0.9f*h_new;
            hbW[b*U_ + u] = h_out;
            seq[(size_t)(b*T_ + t)*U_ + u] = __float2half_rn(h_out);
        }
        gridbar(bar_cnt, bar_gen, nblk);
    }
}

// ---------------- final: out = concat(h2@fw+fb, sigmoid(h2@sw+sb)) -------------
__global__ __launch_bounds__(256) void final_kernel(
    const __half* __restrict__ h2, const float* __restrict__ fw, const float* __restrict__ fb,
    const float* __restrict__ sw, const float* __restrict__ sb, float* __restrict__ out)
{
    __shared__ float hs2[32*1028];
    const int r0 = blockIdx.x * 32;
    const int tid = threadIdx.x;
    for (int i = tid; i < 8192; i += 256) {
        const int r = i >> 8;
        const int k = (i & 255) * 4;
        const __half2* hp = (const __half2*)&h2[(size_t)(r0+r)*1024 + k];
        const float2 f0 = __half22float2(hp[0]);
        const float2 f1 = __half22float2(hp[1]);
        hs2[r*1028 + k+0] = f0.x; hs2[r*1028 + k+1] = f0.y;
        hs2[r*1028 + k+2] = f1.x; hs2[r*1028 + k+3] = f1.y;
    }
    __syncthreads();
    const int j = tid;
    if (j < 161) {
        const bool is_stop = (j == 160);
        float acc[32];
        const float bias = is_stop ? sb[0] : fb[j];
        #pragma unroll
        for (int r=0;r<32;r++) acc[r] = bias;
        for (int k=0;k<1024;k++){
            const float w = is_stop ? sw[k] : fw[k*160 + j];
            #pragma unroll
            for (int r=0;r<32;r++) acc[r] += hs2[r*1028 + k] * w;
        }
        #pragma unroll
        for (int r=0;r<32;r++){
            float v = acc[r];
            if (is_stop) v = sigf(v);
            out[(size_t)(r0+r)*161 + j] = v;
        }
    }
}

extern "C" void kernel_launch(void* const* d_in, const int* in_sizes, int n_in,
                              void* d_out, int out_size, void* d_ws, size_t ws_size,
                              hipStream_t stream)
{
    const float* x    = (const float*)d_in[0];
    const float* pw1  = (const float*)d_in[1];
    const float* pb1  = (const float*)d_in[2];
    const float* pw2  = (const float*)d_in[3];
    const float* pb2  = (const float*)d_in[4];
    const float* wx1  = (const float*)d_in[5];
    const float* wh1  = (const float*)d_in[6];
    const float* a1   = (const float*)d_in[7];
    const float* b11  = (const float*)d_in[8];
    const float* b21  = (const float*)d_in[9];
    const float* bias1= (const float*)d_in[10];
    const float* wx2  = (const float*)d_in[11];
    const float* wh2  = (const float*)d_in[12];
    const float* a2   = (const float*)d_in[13];
    const float* b12  = (const float*)d_in[14];
    const float* b22  = (const float*)d_in[15];
    const float* bias2= (const float*)d_in[16];
    const float* sw   = (const float*)d_in[17];
    const float* sb   = (const float*)d_in[18];
    const float* fw   = (const float*)d_in[19];
    const float* fb   = (const float*)d_in[20];
    float* out = (float*)d_out;

    // ws layout (bytes)
    char* base = (char*)d_ws;
    __half* hseq = (__half*)(base);                    // 26,214,400
    __half* xwc  = (__half*)(base + 26214400);         // 26,214,400
    __half* p    = (__half*)(base + 52428800);         //  6,553,600
    float*  hb0  = (float*) (base + 58982400);         //    131,072
    float*  hb1  = (float*) (base + 59113472);         //    131,072
    float*  cb   = (float*) (base + 59244544);         //    131,072
    __half* whT1 = (__half*)(base + 59375616);         //  8,388,608
    __half* whT2 = (__half*)(base + 67764224);         //  8,388,608
    __half* wxT1 = (__half*)(base + 76152832);         //  2,097,152
    __half* wxT2 = (__half*)(base + 78249984);         //  8,388,608
    int*    bar  = (int*)   (base + 86638592);         //         64 -> 86,638,656
    const size_t NEED = 86638656;
    if (ws_size < NEED) {
        ws_sentinel_kernel<<<(out_size + 255) / 256, 256, 0, stream>>>(out, out_size);
        return;
    }

    // one-time weight prep + barrier zero
    transpose_fp16_kernel<<<dim3(64,16), 256, 0, stream>>>(wh1, whT1, 1024);
    transpose_fp16_kernel<<<dim3(64,16), 256, 0, stream>>>(wh2, whT2, 1024);
    transpose_fp16_kernel<<<dim3(64, 4), 256, 0, stream>>>(wx1, wxT1, 256);
    transpose_fp16_kernel<<<dim3(64,16), 256, 0, stream>>>(wx2, wxT2, 1024);
    hipMemsetAsync(bar, 0, 64, stream);

    prenet_kernel<<<400, 256, 0, stream>>>(x, pw1, pb1, pw2, pb2, p);

    // ---- layer 1 ----
    hipMemsetAsync(hb0, 0, (size_t)3*32768*sizeof(float), stream);
    for (int c = 0; c < NCH; c++) {
        const int t0 = c * TCH;
        gemm_mfma<256><<<dim3(64, 50), 256, 0, stream>>>(p, wxT1, xwc, t0);
        lstm_chunk<<<64, 256, 0, stream>>>(whT1, xwc, a1, b11, b21, bias1,
                                           hb0, hb1, cb, hseq, t0, bar, bar+1);
    }

    // ---- layer 2 (GEMM reads h1 chunk from hseq, persistent steps overwrite with h2) ----
    hipMemsetAsync(hb0, 0, (size_t)3*32768*sizeof(float), stream);
    for (int c = 0; c < NCH; c++) {
        const int t0 = c * TCH;
        gemm_mfma<1024><<<dim3(64, 50), 256, 0, stream>>>(hseq, wxT2, xwc, t0);
        lstm_chunk<<<64, 256, 0, stream>>>(whT2, xwc, a2, b12, b22, bias2,
                                           hb0, hb1, cb, hseq, t0, bar, bar+1);
    }

    final_kernel<<<400, 256, 0, stream>>>(hseq, fw, fb, sw, sb, out);
}

// Round 15
// 6070.392 us; speedup vs baseline: 2.8369x; 2.8369x over previous
//
#include <hip/hip_runtime.h>
#include <hip/hip_fp16.h>
#include <math.h>

#define B_   32
#define T_   400
#define BT_  12800
#define U_   1024
#define G4_  4096

typedef _Float16 f16x8 __attribute__((ext_vector_type(8)));
typedef float    f32x4 __attribute__((ext_vector_type(4)));

__device__ __forceinline__ float sigf(float x){ return 1.0f/(1.0f+expf(-x)); }
__device__ __forceinline__ int f2h2(float a, float b){
    __half2 h = __floats2half2_rn(a, b);
    return __builtin_bit_cast(int, h);
}
__device__ __forceinline__ f16x8 ldg8(const __half* p){
    return *reinterpret_cast<const f16x8*>(p);   // 16B aligned by construction
}

// Diagnostic: ws too small -> absmax ~1000 (distinct from silent-launch-fail 0.5)
__global__ __launch_bounds__(256) void ws_sentinel_kernel(float* __restrict__ out, int n)
{
    const int i = blockIdx.x * 256 + threadIdx.x;
    if (i < n) out[i] = 1000.0f;
}

// ---------------- one-time: WT[c][k] = (fp16) W[k][c], W is [rows][4096] ------
__global__ __launch_bounds__(256) void transpose_fp16_kernel(
    const float* __restrict__ W, __half* __restrict__ WT, int rowsTotal)
{
    __shared__ float tile[64][65];
    const int bx = blockIdx.x;
    const int by = blockIdx.y;
    const int tid = threadIdx.x;
    for (int i = tid; i < 1024; i += 256) {
        const int r  = i >> 4;
        const int c4 = (i & 15) * 4;
        float4 v = *(const float4*)&W[(by*64 + r)*G4_ + bx*64 + c4];
        tile[c4+0][r] = v.x; tile[c4+1][r] = v.y;
        tile[c4+2][r] = v.z; tile[c4+3][r] = v.w;
    }
    __syncthreads();
    for (int i = tid; i < 512; i += 256) {
        const int c  = i >> 3;
        const int r8 = (i & 7) * 8;
        int4 pk;
        pk.x = f2h2(tile[c][r8+0], tile[c][r8+1]);
        pk.y = f2h2(tile[c][r8+2], tile[c][r8+3]);
        pk.z = f2h2(tile[c][r8+4], tile[c][r8+5]);
        pk.w = f2h2(tile[c][r8+6], tile[c][r8+7]);
        *(int4*)&WT[(size_t)(bx*64 + c)*rowsTotal + by*64 + r8] = pk;
    }
}

// ---------------- prenet ----------------
__global__ __launch_bounds__(256) void prenet_kernel(
    const float* __restrict__ x, const float* __restrict__ pw1, const float* __restrict__ pb1,
    const float* __restrict__ pw2, const float* __restrict__ pb2, __half* __restrict__ p)
{
    __shared__ float xs[32*80];
    __shared__ float ys[32*256];
    const int r0 = blockIdx.x * 32;
    const int tid = threadIdx.x;
    for (int i = tid; i < 32*80; i += 256) xs[i] = x[r0*80 + i];
    __syncthreads();
    const int j = tid;
    float acc[32];
    #pragma unroll
    for (int r=0;r<32;r++) acc[r] = pb1[j];
    for (int k=0;k<80;k++){
        float w = pw1[k*256 + j];
        #pragma unroll
        for (int r=0;r<32;r++) acc[r] += xs[r*80+k]*w;
    }
    #pragma unroll
    for (int r=0;r<32;r++) ys[r*256+j] = fmaxf(acc[r], 0.0f);
    __syncthreads();
    #pragma unroll
    for (int r=0;r<32;r++) acc[r] = pb2[j];
    for (int k=0;k<256;k++){
        float w = pw2[k*256 + j];
        #pragma unroll
        for (int r=0;r<32;r++) acc[r] += ys[r*256+k]*w;
    }
    #pragma unroll
    for (int r=0;r<32;r++) p[(r0+r)*256 + j] = __float2half_rn(fmaxf(acc[r], 0.0f));
}

// ---------------- fused dual-layer MI-LSTM step ----------------
// Launch t (0..400), 512 blocks x 256 thr (4 waves):
//   blocks   0..255: layer-1 step s=t   (skip if s>=400)
//   blocks 256..511: layer-2 step s=t-1 (skip if s<0)
// Legality: L2 reads h1seq[s] and h2seq[s-1], both written in launch t-1;
// kernel-boundary coherence, no fences needed.
// Block owns 4 units x 4 gates (16 output cols). Wave wid takes K-slice.
// Computes BOTH matmuls per step: hw (recurrent, K=1024, from seq fp16) and
// xw (input, K=KX, from p(256) or h1seq(1024)), MFMA fp32-accum, LDS reduce,
// fused gate/zoneout epilogue. h carry fp16 via seq; c carry fp32.
__global__ __launch_bounds__(256) void fused_step(
    const __half* __restrict__ whT1, const __half* __restrict__ wxT1,
    const __half* __restrict__ whT2, const __half* __restrict__ wxT2,
    const __half* __restrict__ p,
    __half* __restrict__ h1seq, __half* __restrict__ h2seq,
    const float* __restrict__ a1, const float* __restrict__ b11,
    const float* __restrict__ b21, const float* __restrict__ bias1,
    const float* __restrict__ a2, const float* __restrict__ b12,
    const float* __restrict__ b22, const float* __restrict__ bias2,
    float* __restrict__ c1, float* __restrict__ c2, int t)
{
    const bool isL2 = blockIdx.x >= 256;
    const int s = isL2 ? (t - 1) : t;
    if (s < 0 || s >= T_) return;

    const __half* whT = isL2 ? whT2 : whT1;
    const __half* wiT = isL2 ? wxT2 : wxT1;
    const __half* xin = isL2 ? h1seq : p;       // input-projection source rows
    const int     KX  = isL2 ? 1024 : 256;      // its K
    const __half* hrc = isL2 ? h2seq : h1seq;   // recurrent h source (t-1 rows)
    __half*      seqW = isL2 ? h2seq : h1seq;
    const float* aP   = isL2 ? a2 : a1;
    const float* b1P  = isL2 ? b12 : b11;
    const float* b2P  = isL2 ? b22 : b21;
    const float* bsP  = isL2 ? bias2 : bias1;
    float*       cst  = isL2 ? c2 : c1;

    __shared__ float pt[4][32][17];   // recurrent partials [wave][batch][col]
    __shared__ float px[4][32][17];   // input partials
    const int tid  = threadIdx.x;
    const int wid  = tid >> 6;
    const int lane = tid & 63;
    const int lr   = lane & 15;
    const int kg   = lane >> 4;
    const int u0   = (blockIdx.x & 255) * 4;
    const int lcrow = (lr >> 2)*U_ + u0 + (lr & 3);   // weight row for output col lr

    // recurrent matmul: K=1024, wave slice wid*256 (8 iters)
    f32x4 aH0 = {0,0,0,0}, aH1 = {0,0,0,0};
    if (s > 0) {
        const __half* bp  = &whT[(size_t)lcrow*U_ + wid*256 + kg*8];
        const __half* a0p = &hrc[(size_t)(lr*T_      + s-1)*U_ + wid*256 + kg*8];
        const __half* a1p = &hrc[(size_t)((lr+16)*T_ + s-1)*U_ + wid*256 + kg*8];
        #pragma unroll
        for (int ks = 0; ks < 8; ks++) {
            const f16x8 b  = ldg8(bp  + ks*32);
            const f16x8 x0 = ldg8(a0p + ks*32);
            const f16x8 x1 = ldg8(a1p + ks*32);
            aH0 = __builtin_amdgcn_mfma_f32_16x16x32_f16(x0, b, aH0, 0, 0, 0);
            aH1 = __builtin_amdgcn_mfma_f32_16x16x32_f16(x1, b, aH1, 0, 0, 0);
        }
    }
    // input matmul: K=KX, wave slice wid*(KX/4)
    f32x4 aX0 = {0,0,0,0}, aX1 = {0,0,0,0};
    {
        const int kw = KX >> 2;
        const __half* bp  = &wiT[(size_t)lcrow*KX + wid*kw + kg*8];
        const __half* a0p = &xin[(size_t)(lr*T_      + s)*KX + wid*kw + kg*8];
        const __half* a1p = &xin[(size_t)((lr+16)*T_ + s)*KX + wid*kw + kg*8];
        const int it = kw >> 5;               // 2 (KX=256) or 8 (KX=1024)
        for (int ks = 0; ks < it; ks++) {
            const f16x8 b  = ldg8(bp  + ks*32);
            const f16x8 x0 = ldg8(a0p + ks*32);
            const f16x8 x1 = ldg8(a1p + ks*32);
            aX0 = __builtin_amdgcn_mfma_f32_16x16x32_f16(x0, b, aX0, 0, 0, 0);
            aX1 = __builtin_amdgcn_mfma_f32_16x16x32_f16(x1, b, aX1, 0, 0, 0);
        }
    }
    #pragma unroll
    for (int r = 0; r < 4; r++) {
        pt[wid][kg*4 + r][lr]      = aH0[r];
        pt[wid][16 + kg*4 + r][lr] = aH1[r];
        px[wid][kg*4 + r][lr]      = aX0[r];
        px[wid][16 + kg*4 + r][lr] = aX1[r];
    }
    __syncthreads();

    if (tid < 128) {
        const int bb = tid >> 2;
        const int j  = tid & 3;
        const int u  = u0 + j;
        float z[4];
        #pragma unroll
        for (int g = 0; g < 4; g++) {
            const int lc = g*4 + j;
            const float hw = pt[0][bb][lc] + pt[1][bb][lc] + pt[2][bb][lc] + pt[3][bb][lc];
            const float xw = px[0][bb][lc] + px[1][bb][lc] + px[2][bb][lc] + px[3][bb][lc];
            const int col = g*U_ + u;
            z[g] = aP[col]*xw*hw + b1P[col]*xw + b2P[col]*hw + bsP[col];
        }
        const float c_old = (s > 0) ? cst[bb*U_ + u] : 0.0f;
        const float c_new = sigf(z[1])*c_old + sigf(z[0])*tanhf(z[2]);
        const float h_new = sigf(z[3])*tanhf(c_new);
        cst[bb*U_ + u] = 0.1f*c_old + 0.9f*c_new;
        const float h_prev = (s > 0)
            ? __half2float(seqW[(size_t)(bb*T_ + s-1)*U_ + u]) : 0.0f;
        const float h_out = 0.1f*h_prev + 0.9f*h_new;
        seqW[(size_t)(bb*T_ + s)*U_ + u] = __float2half_rn(h_out);
    }
}

// ---------------- final: out = concat(h2@fw+fb, sigmoid(h2@sw+sb)) -------------
__global__ __launch_bounds__(256) void final_kernel(
    const __half* __restrict__ h2, const float* __restrict__ fw, const float* __restrict__ fb,
    const float* __restrict__ sw, const float* __restrict__ sb, float* __restrict__ out)
{
    __shared__ float hs2[32*1028];
    const int r0 = blockIdx.x * 32;
    const int tid = threadIdx.x;
    for (int i = tid; i < 8192; i += 256) {
        const int r = i >> 8;
        const int k = (i & 255) * 4;
        const __half2* hp = (const __half2*)&h2[(size_t)(r0+r)*1024 + k];
        const float2 f0 = __half22float2(hp[0]);
        const float2 f1 = __half22float2(hp[1]);
        hs2[r*1028 + k+0] = f0.x; hs2[r*1028 + k+1] = f0.y;
        hs2[r*1028 + k+2] = f1.x; hs2[r*1028 + k+3] = f1.y;
    }
    __syncthreads();
    const int j = tid;
    if (j < 161) {
        const bool is_stop = (j == 160);
        float acc[32];
        const float bias = is_stop ? sb[0] : fb[j];
        #pragma unroll
        for (int r=0;r<32;r++) acc[r] = bias;
        for (int k=0;k<1024;k++){
            const float w = is_stop ? sw[k] : fw[k*160 + j];
            #pragma unroll
            for (int r=0;r<32;r++) acc[r] += hs2[r*1028 + k] * w;
        }
        #pragma unroll
        for (int r=0;r<32;r++){
            float v = acc[r];
            if (is_stop) v = sigf(v);
            out[(size_t)(r0+r)*161 + j] = v;
        }
    }
}

extern "C" void kernel_launch(void* const* d_in, const int* in_sizes, int n_in,
                              void* d_out, int out_size, void* d_ws, size_t ws_size,
                              hipStream_t stream)
{
    const float* x    = (const float*)d_in[0];
    const float* pw1  = (const float*)d_in[1];
    const float* pb1  = (const float*)d_in[2];
    const float* pw2  = (const float*)d_in[3];
    const float* pb2  = (const float*)d_in[4];
    const float* wx1  = (const float*)d_in[5];
    const float* wh1  = (const float*)d_in[6];
    const float* a1   = (const float*)d_in[7];
    const float* b11  = (const float*)d_in[8];
    const float* b21  = (const float*)d_in[9];
    const float* bias1= (const float*)d_in[10];
    const float* wx2  = (const float*)d_in[11];
    const float* wh2  = (const float*)d_in[12];
    const float* a2   = (const float*)d_in[13];
    const float* b12  = (const float*)d_in[14];
    const float* b22  = (const float*)d_in[15];
    const float* bias2= (const float*)d_in[16];
    const float* sw   = (const float*)d_in[17];
    const float* sb   = (const float*)d_in[18];
    const float* fw   = (const float*)d_in[19];
    const float* fb   = (const float*)d_in[20];
    float* out = (float*)d_out;

    // ws layout (bytes); total = 86,507,520 (< round-13's verified 86,638,656)
    char* base = (char*)d_ws;
    __half* h1seq = (__half*)(base);                    // 26,214,400
    __half* h2seq = (__half*)(base + 26214400);         // 26,214,400
    __half* p     = (__half*)(base + 52428800);         //  6,553,600
    __half* whT1  = (__half*)(base + 58982400);         //  8,388,608
    __half* whT2  = (__half*)(base + 67371008);         //  8,388,608
    __half* wxT1  = (__half*)(base + 75759616);         //  2,097,152
    __half* wxT2  = (__half*)(base + 77856768);         //  8,388,608
    float*  c1    = (float*) (base + 86245376);         //    131,072
    float*  c2    = (float*) (base + 86376448);         //    131,072 -> 86,507,520
    const size_t NEED = 86507520;
    if (ws_size < NEED) {
        ws_sentinel_kernel<<<(out_size + 255) / 256, 256, 0, stream>>>(out, out_size);
        return;
    }

    // one-time weight prep
    transpose_fp16_kernel<<<dim3(64,16), 256, 0, stream>>>(wh1, whT1, 1024);
    transpose_fp16_kernel<<<dim3(64,16), 256, 0, stream>>>(wh2, whT2, 1024);
    transpose_fp16_kernel<<<dim3(64, 4), 256, 0, stream>>>(wx1, wxT1, 256);
    transpose_fp16_kernel<<<dim3(64,16), 256, 0, stream>>>(wx2, wxT2, 1024);

    prenet_kernel<<<400, 256, 0, stream>>>(x, pw1, pb1, pw2, pb2, p);

    // software-pipelined dual-layer scan: launch t = L1[t] ∥ L2[t-1]
    for (int t = 0; t <= T_; t++) {
        fused_step<<<512, 256, 0, stream>>>(whT1, wxT1, whT2, wxT2, p,
                                            h1seq, h2seq,
                                            a1, b11, b21, bias1,
                                            a2, b12, b22, bias2,
                                            c1, c2, t);
    }

    final_kernel<<<400, 256, 0, stream>>>(h2seq, fw, fb, sw, sb, out);
}